// Round 2
// baseline (1327.718 us; speedup 1.0000x reference)
//
#include <hip/hip_runtime.h>

#define NPER 50000
#define NB 8
#define FIN 64
#define NH1 128
#define NEMB 64

// ---------------- bf16 helpers ----------------
__device__ inline float bf2f(unsigned int u){
  union { unsigned int i; float f; } v; v.i = u << 16; return v.f;
}
__device__ inline unsigned short f2bf(float f){
  union { float f; unsigned int i; } v; v.f = f;
  unsigned int b = v.i + 0x7FFF + ((v.i >> 16) & 1);
  return (unsigned short)(b >> 16);
}

// ---------------- dtype sniffer: is edge_index stored as int64? ----------------
__global__ void k_detect(const int* __restrict__ ei, int* __restrict__ flag){
  __shared__ int any;
  if(threadIdx.x == 0) any = 0;
  __syncthreads();
  for(int i = threadIdx.x; i < 2048; i += 256){
    if(ei[2*i + 1] != 0) any = 1;   // benign race
  }
  __syncthreads();
  if(threadIdx.x == 0) *flag = (any == 0) ? 1 : 0;   // 1 -> int64 storage
}

__device__ inline int load_edge(const int* __restrict__ ei, int idx, bool is64){
  return is64 ? ei[2*idx] : ei[idx];   // little-endian low word
}

// ---------------- degree / dis ----------------
__global__ void k_deg(const int* __restrict__ ei, const int* __restrict__ flag,
                      float* __restrict__ deg, int E){
  int e = blockIdx.x*256 + threadIdx.x;
  if(e < E){
    bool is64 = (*flag != 0);
    int d = load_edge(ei, E + e, is64);
    unsafeAtomicAdd(&deg[d], 1.0f);
  }
}

__global__ void k_dis(float* __restrict__ deg, int n){
  int i = blockIdx.x*256 + threadIdx.x;
  if(i < n) deg[i] = rsqrtf(deg[i] + 1.0f);   // +1 = self loop
}

// ---------------- GEMM1 block: g[:,qC:qC+C] = (x @ W1[:,qC:qC+C]) * dis ----------------
template<int C>
__global__ __launch_bounds__(256) void k_gemm1(const float* __restrict__ x, const float* __restrict__ W,
                                               const float* __restrict__ dis, float* __restrict__ g,
                                               int n, int q){
  __shared__ float4 ws4[64*C/4];
  for(int idx = threadIdx.x; idx < 64*C/4; idx += 256){
    int k = idx/(C/4), c4 = idx%(C/4);
    ws4[idx] = *(const float4*)(W + k*NH1 + q*C + c4*4);
  }
  __syncthreads();
  int node = blockIdx.x*256 + threadIdx.x;
  if(node >= n) return;
  const float4* xr = (const float4*)(x + (size_t)node*FIN);
  float4 acc[C/4] = {};
  for(int j = 0; j < 16; j++){
    float4 xq = xr[j];
    #pragma unroll
    for(int kk = 0; kk < 4; kk++){
      float xs = (kk==0) ? xq.x : (kk==1) ? xq.y : (kk==2) ? xq.z : xq.w;
      const float4* wrow = &ws4[(j*4+kk)*(C/4)];
      #pragma unroll
      for(int c = 0; c < C/4; c++){
        float4 w = wrow[c];
        acc[c].x = fmaf(xs, w.x, acc[c].x);
        acc[c].y = fmaf(xs, w.y, acc[c].y);
        acc[c].z = fmaf(xs, w.z, acc[c].z);
        acc[c].w = fmaf(xs, w.w, acc[c].w);
      }
    }
  }
  float d = dis[node];
  float4* go = (float4*)(g + (size_t)node*C);
  #pragma unroll
  for(int c = 0; c < C/4; c++){
    float4 r = acc[c];
    r.x *= d; r.y *= d; r.z *= d; r.w *= d;
    go[c] = r;
  }
}

// ---------------- GEMM2 block: g[:,qC:qC+C] = (x1 @ W2[:,qC:qC+C]) * dis, x1 bf16 ----------------
template<int C>
__global__ __launch_bounds__(256) void k_gemm2(const unsigned short* __restrict__ x1, const float* __restrict__ W,
                                               const float* __restrict__ dis, float* __restrict__ g,
                                               int n, int q){
  __shared__ float4 ws4[128*C/4];
  for(int idx = threadIdx.x; idx < 128*C/4; idx += 256){
    int k = idx/(C/4), c4 = idx%(C/4);
    ws4[idx] = *(const float4*)(W + k*NEMB + q*C + c4*4);
  }
  __syncthreads();
  int node = blockIdx.x*256 + threadIdx.x;
  if(node >= n) return;
  const uint4* xr = (const uint4*)(x1 + (size_t)node*NH1);
  float4 acc[C/4] = {};
  for(int j = 0; j < 16; j++){        // 16 x 8 bf16 = 128
    uint4 u = xr[j];
    float xs[8];
    xs[0] = bf2f(u.x & 0xFFFFu); xs[1] = bf2f(u.x >> 16);
    xs[2] = bf2f(u.y & 0xFFFFu); xs[3] = bf2f(u.y >> 16);
    xs[4] = bf2f(u.z & 0xFFFFu); xs[5] = bf2f(u.z >> 16);
    xs[6] = bf2f(u.w & 0xFFFFu); xs[7] = bf2f(u.w >> 16);
    #pragma unroll
    for(int kk = 0; kk < 8; kk++){
      const float4* wrow = &ws4[(j*8+kk)*(C/4)];
      #pragma unroll
      for(int c = 0; c < C/4; c++){
        float4 w = wrow[c];
        acc[c].x = fmaf(xs[kk], w.x, acc[c].x);
        acc[c].y = fmaf(xs[kk], w.y, acc[c].y);
        acc[c].z = fmaf(xs[kk], w.z, acc[c].z);
        acc[c].w = fmaf(xs[kk], w.w, acc[c].w);
      }
    }
  }
  float d = dis[node];
  float4* go = (float4*)(g + (size_t)node*C);
  #pragma unroll
  for(int c = 0; c < C/4; c++){
    float4 r = acc[c];
    r.x *= d; r.y *= d; r.z *= d; r.w *= d;
    go[c] = r;
  }
}

// ---------------- edge scatter: t[dst][0:C] += g[src][0:C] ----------------
template<int C>
__global__ void k_scatter(const int* __restrict__ ei, const int* __restrict__ flag,
                          const float* __restrict__ g, float* __restrict__ t, int E){
  const int EPB = 256 / C;
  int e = blockIdx.x * EPB + (threadIdx.x / C);
  int c = threadIdx.x % C;
  if(e >= E) return;
  bool is64 = (*flag != 0);
  int s = load_edge(ei, e, is64);
  int d = load_edge(ei, E + e, is64);
  unsafeAtomicAdd(&t[(size_t)d*C + c], g[(size_t)s*C + c]);
}

// ---------------- combine layer1 block -> x1 (bf16): relu(dis*(t+g)+b1) ----------------
template<int C>
__global__ void k_comb1(const float* __restrict__ t1, const float* __restrict__ g1,
                        const float* __restrict__ dis, const float* __restrict__ b1,
                        unsigned short* __restrict__ x1, int n, int q){
  int idx = blockIdx.x*256 + threadIdx.x;     // float4 group index
  if(idx >= n*(C/4)) return;
  int node = idx/(C/4), c4 = idx%(C/4);
  float4 t = ((const float4*)t1)[idx];
  float4 g = ((const float4*)g1)[idx];
  float4 b = *(const float4*)(b1 + q*C + c4*4);
  float d = dis[node];
  ushort4 o;
  o.x = f2bf(fmaxf(fmaf(d, t.x + g.x, b.x), 0.f));
  o.y = f2bf(fmaxf(fmaf(d, t.y + g.y, b.y), 0.f));
  o.z = f2bf(fmaxf(fmaf(d, t.z + g.z, b.z), 0.f));
  o.w = f2bf(fmaxf(fmaf(d, t.w + g.w, b.w), 0.f));
  *(ushort4*)(x1 + (size_t)node*NH1 + q*C + c4*4) = o;
}

// ---------------- pool block: pooled[b][qC+c] += sum relu(dis*(t2+g2)+b2) ----------------
template<int C>
__global__ void k_pool(const float* __restrict__ g2, const float* __restrict__ t2,
                       const float* __restrict__ dis, const float* __restrict__ b2,
                       float* __restrict__ pooled, int q){
  const int CH = 782;                          // 64 chunks * 782 >= 50000
  const int SUBS = 256 / C;
  int chunk = blockIdx.x;                      // 0..63
  int b = blockIdx.y;                          // 0..7
  int c = threadIdx.x % C, sub = threadIdx.x / C;
  float bc = b2[q*C + c];
  float acc = 0.f;
  int lo = chunk*CH;
  int hi = lo + CH; if(hi > NPER) hi = NPER;
  for(int i = lo + sub; i < hi; i += SUBS){
    int node = b*NPER + i;
    size_t off = (size_t)node*C + c;
    acc += fmaxf(fmaf(dis[node], t2[off] + g2[off], bc), 0.f);
  }
  __shared__ float red[256];
  red[threadIdx.x] = acc;
  __syncthreads();
  if(sub == 0){
    float s = 0.f;
    #pragma unroll
    for(int k = 0; k < SUBS; k++) s += red[k*C + c];
    unsafeAtomicAdd(&pooled[b*64 + q*C + c], s);
  }
}

// ---------------- head: out = relu(mean @ fc_w + fc_b) @ out_w + out_b ----------------
__global__ void k_head(const float* __restrict__ pooled, const float* __restrict__ fcw,
                       const float* __restrict__ fcb, const float* __restrict__ ow,
                       const float* __restrict__ ob, float* __restrict__ out){
  __shared__ float p[NB*NEMB];
  __shared__ float h[NB*NEMB];
  int t = threadIdx.x;                         // 0..511
  p[t] = pooled[t] * (1.0f / (float)NPER);
  __syncthreads();
  int b = t >> 6, j = t & 63;
  float a = fcb[j];
  #pragma unroll 8
  for(int c = 0; c < 64; c++) a = fmaf(p[b*64+c], fcw[c*64+j], a);
  h[t] = fmaxf(a, 0.f);
  __syncthreads();
  float o = ob[j];
  #pragma unroll 8
  for(int c = 0; c < 64; c++) o = fmaf(h[b*64+c], ow[c*64+j], o);
  out[t] = o;
}

// ---------------- host-side pipeline, templated on channel block C ----------------
template<int C>
static void run_all(const float* x, const int* ei,
                    const float* W1, const float* b1, const float* W2, const float* b2,
                    const float* fcw, const float* fcb, const float* ow, const float* ob,
                    float* d_out, float* ws, int n, int E, hipStream_t stream){
  float* dis    = ws;                               // n floats
  int*   flag   = (int*)(ws + n);                   // 1 int
  float* pooled = ws + n + 256;                     // 512 floats
  unsigned short* x1 = (unsigned short*)(ws + n + 1024);        // n*128 bf16
  float* gq = (float*)((char*)x1 + (size_t)n*NH1*2);            // n*C fp32
  float* tq = gq + (size_t)n*C;                                 // n*C fp32

  hipMemsetAsync(dis, 0, (size_t)n*sizeof(float), stream);
  hipMemsetAsync(pooled, 0, NB*NEMB*sizeof(float), stream);

  k_detect<<<1, 256, 0, stream>>>(ei, flag);
  k_deg<<<(E+255)/256, 256, 0, stream>>>(ei, flag, dis, E);
  k_dis<<<(n+255)/256, 256, 0, stream>>>(dis, n);

  const int gemm_blocks = (n + 255)/256;
  const int EPB = 256 / C;
  const int sc_blocks = (E + EPB - 1)/EPB;
  const int cb_blocks = (n*(C/4) + 255)/256;
  dim3 pgrid(64, NB);

  // layer 1: NH1/C channel blocks
  for(int q = 0; q < NH1/C; q++){
    k_gemm1<C><<<gemm_blocks, 256, 0, stream>>>(x, W1, dis, gq, n, q);
    hipMemsetAsync(tq, 0, (size_t)n*C*sizeof(float), stream);
    k_scatter<C><<<sc_blocks, 256, 0, stream>>>(ei, flag, gq, tq, E);
    k_comb1<C><<<cb_blocks, 256, 0, stream>>>(tq, gq, dis, b1, x1, n, q);
  }
  // layer 2: NEMB/C channel blocks
  for(int q = 0; q < NEMB/C; q++){
    k_gemm2<C><<<gemm_blocks, 256, 0, stream>>>(x1, W2, dis, gq, n, q);
    hipMemsetAsync(tq, 0, (size_t)n*C*sizeof(float), stream);
    k_scatter<C><<<sc_blocks, 256, 0, stream>>>(ei, flag, gq, tq, E);
    k_pool<C><<<pgrid, 256, 0, stream>>>(gq, tq, dis, b2, pooled, q);
  }
  k_head<<<1, 512, 0, stream>>>(pooled, fcw, fcb, ow, ob, d_out);
}

extern "C" void kernel_launch(void* const* d_in, const int* in_sizes, int n_in,
                              void* d_out, int out_size, void* d_ws, size_t ws_size,
                              hipStream_t stream){
  const float* x   = (const float*)d_in[0];
  const int*   ei  = (const int*)d_in[1];
  const float* W1  = (const float*)d_in[2];
  const float* b1  = (const float*)d_in[3];
  const float* W2  = (const float*)d_in[4];
  const float* b2  = (const float*)d_in[5];
  const float* fcw = (const float*)d_in[6];
  const float* fcb = (const float*)d_in[7];
  const float* ow  = (const float*)d_in[8];
  const float* ob  = (const float*)d_in[9];

  const int n = in_sizes[0] / FIN;   // 400000 nodes
  const int E = in_sizes[1] / 2;     // 400000 edges

  // workspace need: (n+1024) fp32 + n*128 bf16 (x1) + 2 * n*C fp32 (g,t)
  size_t base = (size_t)(n + 1024)*4 + (size_t)n*NH1*2;
  size_t need32 = base + 2*(size_t)n*32*4;   // ~206.4 MB
  if(ws_size >= need32){
    run_all<32>(x, ei, W1, b1, W2, b2, fcw, fcb, ow, ob, (float*)d_out, (float*)d_ws, n, E, stream);
  }else{
    run_all<16>(x, ei, W1, b1, W2, b2, fcw, fcb, ow, ob, (float*)d_out, (float*)d_ws, n, E, stream);
  }
}

// Round 3
// 570.570 us; speedup vs baseline: 2.3270x; 2.3270x over previous
//
#include <hip/hip_runtime.h>

#define NPER 50000
#define NB 8
#define FIN 64
#define NH1 128
#define NEMB 64

// ---------------- bf16 helpers ----------------
__device__ inline float bf2f(unsigned int u){ union{unsigned int i; float f;} v; v.i = u<<16; return v.f; }
__device__ inline unsigned int f2bf1(float f){ union{float f; unsigned int i;} v; v.f = f;
  return (v.i + 0x7FFFu + ((v.i>>16)&1u)) >> 16; }
__device__ inline unsigned int packbf(float lo, float hi){ return f2bf1(lo) | (f2bf1(hi)<<16); }
__device__ inline void unp8add(float* s, uint4 q){
  s[0]+=bf2f(q.x&0xFFFFu); s[1]+=bf2f(q.x>>16);
  s[2]+=bf2f(q.y&0xFFFFu); s[3]+=bf2f(q.y>>16);
  s[4]+=bf2f(q.z&0xFFFFu); s[5]+=bf2f(q.z>>16);
  s[6]+=bf2f(q.w&0xFFFFu); s[7]+=bf2f(q.w>>16);
}

// ---------------- dtype sniffer: is edge_index stored as int64? ----------------
__global__ void k_detect(const int* __restrict__ ei, int* __restrict__ flag){
  __shared__ int any;
  if(threadIdx.x == 0) any = 0;
  __syncthreads();
  for(int i = threadIdx.x; i < 2048; i += 256){
    if(ei[2*i + 1] != 0) any = 1;   // benign race
  }
  __syncthreads();
  if(threadIdx.x == 0) *flag = (any == 0) ? 1 : 0;   // 1 -> int64 storage
}
__device__ inline int load_edge(const int* __restrict__ ei, int idx, bool is64){
  return is64 ? ei[2*idx] : ei[idx];   // little-endian low word
}

// ---------------- in-degree count ----------------
__global__ void k_count(const int* __restrict__ ei, const int* __restrict__ flag,
                        int* __restrict__ ideg, int E){
  int e = blockIdx.x*256 + threadIdx.x;
  if(e < E){
    bool is64 = (*flag != 0);
    int d = load_edge(ei, E + e, is64);
    atomicAdd(&ideg[d], 1);
  }
}

// ---------------- prefix sum (3 kernels, 1024 items/block) ----------------
__global__ void k_scan1(const int* __restrict__ ideg, int* __restrict__ bsum, int n){
  __shared__ int red[256];
  int i0 = blockIdx.x*1024 + threadIdx.x*4;
  int t = 0;
  #pragma unroll
  for(int j = 0; j < 4; j++) if(i0+j < n) t += ideg[i0+j];
  red[threadIdx.x] = t;
  __syncthreads();
  for(int off = 128; off > 0; off >>= 1){
    if(threadIdx.x < off) red[threadIdx.x] += red[threadIdx.x + off];
    __syncthreads();
  }
  if(threadIdx.x == 0) bsum[blockIdx.x] = red[0];
}

__global__ void k_scan2(int* __restrict__ bsum, int* __restrict__ row_start, int nblk, int n){
  if(threadIdx.x == 0){
    int tot = 0;
    for(int b = 0; b < nblk; b++){ int t = bsum[b]; bsum[b] = tot; tot += t; }
    row_start[n] = tot;
  }
}

__global__ void k_scan3(const int* __restrict__ ideg, const int* __restrict__ bsum,
                        int* __restrict__ row_start, int* __restrict__ cursor, int n){
  __shared__ int red[256];
  int i0 = blockIdx.x*1024 + threadIdx.x*4;
  int v[4]; int t = 0;
  #pragma unroll
  for(int j = 0; j < 4; j++){ v[j] = (i0+j < n) ? ideg[i0+j] : 0; t += v[j]; }
  red[threadIdx.x] = t;
  __syncthreads();
  for(int off = 1; off < 256; off <<= 1){
    int a = (threadIdx.x >= off) ? red[threadIdx.x - off] : 0;
    __syncthreads();
    red[threadIdx.x] += a;
    __syncthreads();
  }
  int run = bsum[blockIdx.x] + red[threadIdx.x] - t;
  #pragma unroll
  for(int j = 0; j < 4; j++){
    if(i0+j < n){ row_start[i0+j] = run; cursor[i0+j] = run; run += v[j]; }
  }
}

__global__ void k_dis(const int* __restrict__ ideg, float* __restrict__ dis, int n){
  int i = blockIdx.x*256 + threadIdx.x;
  if(i < n) dis[i] = rsqrtf((float)ideg[i] + 1.0f);   // +1 = self loop
}

__global__ void k_fill(const int* __restrict__ ei, const int* __restrict__ flag,
                       int* __restrict__ cursor, int* __restrict__ src_list, int E){
  int e = blockIdx.x*256 + threadIdx.x;
  if(e < E){
    bool is64 = (*flag != 0);
    int s = load_edge(ei, e, is64);
    int d = load_edge(ei, E + e, is64);
    int pos = atomicAdd(&cursor[d], 1);
    src_list[pos] = s;
  }
}

// ---------------- GEMM1: g1[n,128]bf16 = (x @ W1) * dis ----------------
// block: 256 thr, 128 nodes, all 128 cols. x staged transposed in LDS (coalesced).
__global__ __launch_bounds__(256) void k_gemm1(const float* __restrict__ x, const float* __restrict__ W,
                                               const float* __restrict__ dis,
                                               unsigned int* __restrict__ g1, int n){
  __shared__ float xT[64*132];     // [k][node], pad 132
  __shared__ float wl[64*128];     // [k][c]
  const int tid = threadIdx.x;
  const int base = blockIdx.x*128;
  for(int i = tid; i < 64*128/4; i += 256) ((float4*)wl)[i] = ((const float4*)W)[i];
  for(int i = tid; i < 2048; i += 256){
    int node = i >> 4, c4 = i & 15;
    int gn = base + node;
    float4 v = (gn < n) ? ((const float4*)(x + (size_t)gn*FIN))[c4] : make_float4(0.f,0.f,0.f,0.f);
    xT[(c4*4+0)*132 + node] = v.x;
    xT[(c4*4+1)*132 + node] = v.y;
    xT[(c4*4+2)*132 + node] = v.z;
    xT[(c4*4+3)*132 + node] = v.w;
  }
  __syncthreads();
  const int lane = tid & 63, cq = tid >> 6;   // wave cq -> cols cq*32..+32
  float4 acc[2][8] = {};
  #pragma unroll 4
  for(int k = 0; k < 64; k++){
    float xs0 = xT[k*132 + lane];
    float xs1 = xT[k*132 + 64 + lane];
    const float4* wr = (const float4*)(wl + k*128 + cq*32);
    #pragma unroll
    for(int c = 0; c < 8; c++){
      float4 w = wr[c];
      acc[0][c].x = fmaf(xs0, w.x, acc[0][c].x);
      acc[0][c].y = fmaf(xs0, w.y, acc[0][c].y);
      acc[0][c].z = fmaf(xs0, w.z, acc[0][c].z);
      acc[0][c].w = fmaf(xs0, w.w, acc[0][c].w);
      acc[1][c].x = fmaf(xs1, w.x, acc[1][c].x);
      acc[1][c].y = fmaf(xs1, w.y, acc[1][c].y);
      acc[1][c].z = fmaf(xs1, w.z, acc[1][c].z);
      acc[1][c].w = fmaf(xs1, w.w, acc[1][c].w);
    }
  }
  #pragma unroll
  for(int r = 0; r < 2; r++){
    int gn = base + r*64 + lane;
    if(gn >= n) continue;
    float d = dis[gn];
    unsigned int ob[16];
    #pragma unroll
    for(int c = 0; c < 8; c++){
      float4 a = acc[r][c];
      ob[2*c]   = packbf(a.x*d, a.y*d);
      ob[2*c+1] = packbf(a.z*d, a.w*d);
    }
    uint4* dst = (uint4*)(g1 + (size_t)gn*64 + cq*16);
    dst[0] = make_uint4(ob[0],ob[1],ob[2],ob[3]);
    dst[1] = make_uint4(ob[4],ob[5],ob[6],ob[7]);
    dst[2] = make_uint4(ob[8],ob[9],ob[10],ob[11]);
    dst[3] = make_uint4(ob[12],ob[13],ob[14],ob[15]);
  }
}

// ---------------- fused layer1-aggregate + GEMM2 ----------------
// block: 256 thr, 128 nodes. Stage A: 2 thr/node gather-sum g1[src] halves, combine+ReLU
// -> x1 tile in LDS (bf16, transposed). Stage B: lane-tiled GEMM x1 @ W2 -> g2 bf16.
__global__ __launch_bounds__(256) void k_fused1(const unsigned int* __restrict__ g1,
                                                const float* __restrict__ W2,
                                                const float* __restrict__ dis, const float* __restrict__ b1,
                                                const int* __restrict__ row_start, const int* __restrict__ src_list,
                                                unsigned int* __restrict__ g2, int n){
  __shared__ unsigned int x1T[64*132];  // [k2][node] u32 (2 bf16), pad 132
  __shared__ float wl[128*64];          // [k][c]
  const int tid = threadIdx.x;
  const int base = blockIdx.x*128;
  for(int i = tid; i < 128*64/4; i += 256) ((float4*)wl)[i] = ((const float4*)W2)[i];
  {
    int ln = tid >> 1, half = tid & 1;
    int node = base + ln;
    if(node < n){
      float s[64];
      #pragma unroll
      for(int j = 0; j < 64; j++) s[j] = 0.f;
      const uint4* self = (const uint4*)(g1 + (size_t)node*64 + half*32);
      #pragma unroll
      for(int t = 0; t < 8; t++) unp8add(s + t*8, self[t]);
      int r0 = row_start[node], r1 = row_start[node+1];
      for(int e = r0; e < r1; e++){
        int src = src_list[e];
        const uint4* p = (const uint4*)(g1 + (size_t)src*64 + half*32);
        #pragma unroll
        for(int t = 0; t < 8; t++) unp8add(s + t*8, p[t]);
      }
      float d = dis[node];
      const float* bb = b1 + half*64;
      #pragma unroll
      for(int j = 0; j < 32; j++){
        float v0 = fmaxf(fmaf(d, s[2*j],   bb[2*j]),   0.f);
        float v1 = fmaxf(fmaf(d, s[2*j+1], bb[2*j+1]), 0.f);
        x1T[(half*32 + j)*132 + ln] = packbf(v0, v1);
      }
    }else{
      #pragma unroll
      for(int j = 0; j < 32; j++) x1T[(half*32 + j)*132 + ln] = 0u;
    }
  }
  __syncthreads();
  const int lane = tid & 63, cq = tid >> 6;  // wave cq -> cols cq*16..+16
  float4 acc[2][4] = {};
  #pragma unroll 4
  for(int k2 = 0; k2 < 64; k2++){
    unsigned int u0 = x1T[k2*132 + lane];
    unsigned int u1 = x1T[k2*132 + 64 + lane];
    float a0 = bf2f(u0 & 0xFFFFu), a1 = bf2f(u0 >> 16);
    float b0 = bf2f(u1 & 0xFFFFu), b1v = bf2f(u1 >> 16);
    const float4* wr0 = (const float4*)(wl + (2*k2  )*64 + cq*16);
    const float4* wr1 = (const float4*)(wl + (2*k2+1)*64 + cq*16);
    #pragma unroll
    for(int c = 0; c < 4; c++){
      float4 w0 = wr0[c], w1 = wr1[c];
      acc[0][c].x = fmaf(a0, w0.x, fmaf(a1, w1.x, acc[0][c].x));
      acc[0][c].y = fmaf(a0, w0.y, fmaf(a1, w1.y, acc[0][c].y));
      acc[0][c].z = fmaf(a0, w0.z, fmaf(a1, w1.z, acc[0][c].z));
      acc[0][c].w = fmaf(a0, w0.w, fmaf(a1, w1.w, acc[0][c].w));
      acc[1][c].x = fmaf(b0, w0.x, fmaf(b1v, w1.x, acc[1][c].x));
      acc[1][c].y = fmaf(b0, w0.y, fmaf(b1v, w1.y, acc[1][c].y));
      acc[1][c].z = fmaf(b0, w0.z, fmaf(b1v, w1.z, acc[1][c].z));
      acc[1][c].w = fmaf(b0, w0.w, fmaf(b1v, w1.w, acc[1][c].w));
    }
  }
  #pragma unroll
  for(int r = 0; r < 2; r++){
    int gn = base + r*64 + lane;
    if(gn >= n) continue;
    float d = dis[gn];
    unsigned int ob[8];
    #pragma unroll
    for(int c = 0; c < 4; c++){
      float4 a = acc[r][c];
      ob[2*c]   = packbf(a.x*d, a.y*d);
      ob[2*c+1] = packbf(a.z*d, a.w*d);
    }
    uint4* dst = (uint4*)(g2 + (size_t)gn*32 + cq*8);
    dst[0] = make_uint4(ob[0],ob[1],ob[2],ob[3]);
    dst[1] = make_uint4(ob[4],ob[5],ob[6],ob[7]);
  }
}

// ---------------- fused layer2-aggregate: out2 = relu(dis*(gather+self)+b2), bf16 ----------------
__global__ __launch_bounds__(256) void k_fused2(const unsigned int* __restrict__ g2,
                                                const float* __restrict__ dis, const float* __restrict__ b2,
                                                const int* __restrict__ row_start, const int* __restrict__ src_list,
                                                unsigned int* __restrict__ out2, int n){
  int node = blockIdx.x*256 + threadIdx.x;
  if(node >= n) return;
  float s[64];
  #pragma unroll
  for(int j = 0; j < 64; j++) s[j] = 0.f;
  const uint4* self = (const uint4*)(g2 + (size_t)node*32);
  #pragma unroll
  for(int t = 0; t < 8; t++) unp8add(s + t*8, self[t]);
  int r0 = row_start[node], r1 = row_start[node+1];
  for(int e = r0; e < r1; e++){
    int src = src_list[e];
    const uint4* p = (const uint4*)(g2 + (size_t)src*32);
    #pragma unroll
    for(int t = 0; t < 8; t++) unp8add(s + t*8, p[t]);
  }
  float d = dis[node];
  unsigned int ob[32];
  #pragma unroll
  for(int j = 0; j < 32; j++){
    float v0 = fmaxf(fmaf(d, s[2*j],   b2[2*j]),   0.f);
    float v1 = fmaxf(fmaf(d, s[2*j+1], b2[2*j+1]), 0.f);
    ob[j] = packbf(v0, v1);
  }
  uint4* dst = (uint4*)(out2 + (size_t)node*32);
  #pragma unroll
  for(int t = 0; t < 8; t++) dst[t] = make_uint4(ob[4*t],ob[4*t+1],ob[4*t+2],ob[4*t+3]);
}

// ---------------- pool: pooled[b][c] = sum over nodes of out2 ----------------
__global__ void k_pool(const unsigned int* __restrict__ out2, float* __restrict__ pooled){
  const int CH = 782;                       // 64 chunks * 782 >= 50000
  int chunk = blockIdx.x, b = blockIdx.y;
  int c2 = threadIdx.x & 31, sub = threadIdx.x >> 5;  // 32 u32-cols x 8 rows
  float ax = 0.f, ay = 0.f;
  int lo = chunk*CH, hi = lo + CH; if(hi > NPER) hi = NPER;
  for(int i = lo + sub; i < hi; i += 8){
    int node = b*NPER + i;
    unsigned int u = out2[(size_t)node*32 + c2];
    ax += bf2f(u & 0xFFFFu); ay += bf2f(u >> 16);
  }
  __shared__ float rx[256], ry[256];
  rx[threadIdx.x] = ax; ry[threadIdx.x] = ay;
  __syncthreads();
  if(sub == 0){
    float sx = 0.f, sy = 0.f;
    #pragma unroll
    for(int k = 0; k < 8; k++){ sx += rx[k*32 + c2]; sy += ry[k*32 + c2]; }
    unsafeAtomicAdd(&pooled[b*64 + c2*2],     sx);
    unsafeAtomicAdd(&pooled[b*64 + c2*2 + 1], sy);
  }
}

// ---------------- head: out = relu(mean @ fc_w + fc_b) @ out_w + out_b ----------------
__global__ void k_head(const float* __restrict__ pooled, const float* __restrict__ fcw,
                       const float* __restrict__ fcb, const float* __restrict__ ow,
                       const float* __restrict__ ob, float* __restrict__ out){
  __shared__ float p[NB*NEMB];
  __shared__ float h[NB*NEMB];
  int t = threadIdx.x;                      // 0..511
  p[t] = pooled[t] * (1.0f / (float)NPER);
  __syncthreads();
  int b = t >> 6, j = t & 63;
  float a = fcb[j];
  #pragma unroll 8
  for(int c = 0; c < 64; c++) a = fmaf(p[b*64+c], fcw[c*64+j], a);
  h[t] = fmaxf(a, 0.f);
  __syncthreads();
  float o = ob[j];
  #pragma unroll 8
  for(int c = 0; c < 64; c++) o = fmaf(h[b*64+c], ow[c*64+j], o);
  out[t] = o;
}

extern "C" void kernel_launch(void* const* d_in, const int* in_sizes, int n_in,
                              void* d_out, int out_size, void* d_ws, size_t ws_size,
                              hipStream_t stream){
  const float* x   = (const float*)d_in[0];
  const int*   ei  = (const int*)d_in[1];
  const float* W1  = (const float*)d_in[2];
  const float* b1  = (const float*)d_in[3];
  const float* W2  = (const float*)d_in[4];
  const float* b2  = (const float*)d_in[5];
  const float* fcw = (const float*)d_in[6];
  const float* fcb = (const float*)d_in[7];
  const float* ow  = (const float*)d_in[8];
  const float* ob  = (const float*)d_in[9];

  const int n = in_sizes[0] / FIN;   // 400000 nodes
  const int E = in_sizes[1] / 2;     // 400000 edges

  char* p = (char*)d_ws;
  auto alloc = [&](size_t bytes){ char* r = p; p += (bytes + 255) & ~(size_t)255; return r; };
  float* dis      = (float*)alloc((size_t)n*4);
  int*   ideg     = (int*)  alloc((size_t)n*4);
  int*   row_start= (int*)  alloc((size_t)(n+1)*4);
  int*   cursor   = (int*)  alloc((size_t)n*4);
  int*   bsum     = (int*)  alloc(4096);
  int*   flag     = (int*)  alloc(256);
  float* pooled   = (float*)alloc(2048);
  int*   src_list = (int*)  alloc((size_t)E*4);
  unsigned int* g1 = (unsigned int*)alloc((size_t)n*64*4);   // [n,128] bf16
  unsigned int* g2 = (unsigned int*)alloc((size_t)n*32*4);   // [n,64]  bf16
  unsigned int* out2 = g1;                                   // reuse (g1 dead by then)

  hipMemsetAsync(ideg, 0, (size_t)n*4, stream);
  hipMemsetAsync(pooled, 0, 2048, stream);

  k_detect<<<1, 256, 0, stream>>>(ei, flag);
  k_count<<<(E+255)/256, 256, 0, stream>>>(ei, flag, ideg, E);
  int nblk = (n + 1023)/1024;
  k_scan1<<<nblk, 256, 0, stream>>>(ideg, bsum, n);
  k_scan2<<<1, 64, 0, stream>>>(bsum, row_start, nblk, n);
  k_scan3<<<nblk, 256, 0, stream>>>(ideg, bsum, row_start, cursor, n);
  k_dis<<<(n+255)/256, 256, 0, stream>>>(ideg, dis, n);
  k_fill<<<(E+255)/256, 256, 0, stream>>>(ei, flag, cursor, src_list, E);

  k_gemm1<<<(n+127)/128, 256, 0, stream>>>(x, W1, dis, g1, n);
  k_fused1<<<(n+127)/128, 256, 0, stream>>>(g1, W2, dis, b1, row_start, src_list, g2, n);
  k_fused2<<<(n+255)/256, 256, 0, stream>>>(g2, dis, b2, row_start, src_list, out2, n);

  dim3 pgrid(64, NB);
  k_pool<<<pgrid, 256, 0, stream>>>(out2, pooled);
  k_head<<<1, 512, 0, stream>>>(pooled, fcw, fcb, ow, ob, (float*)d_out);
}

// Round 4
// 392.308 us; speedup vs baseline: 3.3844x; 1.4544x over previous
//
#include <hip/hip_runtime.h>

#define NPER 50000
#define NB 8
#define FIN 64
#define NH1 128
#define NEMB 64

typedef __attribute__((ext_vector_type(8))) short short8;
typedef __attribute__((ext_vector_type(4))) float f32x4;
union U4S8 { uint4 q; short8 s; };

// ---------------- bf16 helpers ----------------
__device__ inline float bf2f(unsigned int u){ union{unsigned int i; float f;} v; v.i = u<<16; return v.f; }
__device__ inline unsigned int f2bf1(float f){ union{float f; unsigned int i;} v; v.f = f;
  return (v.i + 0x7FFFu + ((v.i>>16)&1u)) >> 16; }
__device__ inline unsigned int packbf(float lo, float hi){ return f2bf1(lo) | (f2bf1(hi)<<16); }
__device__ inline void unp8add(float* s, uint4 q){
  s[0]+=bf2f(q.x&0xFFFFu); s[1]+=bf2f(q.x>>16);
  s[2]+=bf2f(q.y&0xFFFFu); s[3]+=bf2f(q.y>>16);
  s[4]+=bf2f(q.z&0xFFFFu); s[5]+=bf2f(q.z>>16);
  s[6]+=bf2f(q.w&0xFFFFu); s[7]+=bf2f(q.w>>16);
}

// ---------------- dtype sniffer: is edge_index stored as int64? ----------------
__global__ void k_detect(const int* __restrict__ ei, int* __restrict__ flag){
  __shared__ int any;
  if(threadIdx.x == 0) any = 0;
  __syncthreads();
  for(int i = threadIdx.x; i < 2048; i += 256){
    if(ei[2*i + 1] != 0) any = 1;   // benign race
  }
  __syncthreads();
  if(threadIdx.x == 0) *flag = (any == 0) ? 1 : 0;   // 1 -> int64 storage
}
__device__ inline int load_edge(const int* __restrict__ ei, int idx, bool is64){
  return is64 ? ei[2*idx] : ei[idx];   // little-endian low word
}

// ---------------- W fragment pre-pack (bf16, MFMA B-operand order) ----------------
// k-mapping CHOSEN as k = kb*32 + 8*(lane/16) + i; A-frags use the same mapping, so
// the contraction is correct for any internal HW k-permutation.
__global__ void k_packW(const float* __restrict__ W1, const float* __restrict__ W2,
                        unsigned int* __restrict__ w1p, unsigned int* __restrict__ w2p){
  int tid = threadIdx.x;
  for(int s = tid; s < 1024; s += 256){          // W1: 8 nt x 2 kb frags
    int f = s >> 6, lane = s & 63;
    int nt = f >> 1, kb = f & 1, g = lane >> 4, c = nt*16 + (lane & 15);
    unsigned int o[4];
    #pragma unroll
    for(int j = 0; j < 4; j++){
      int k0 = kb*32 + g*8 + 2*j;
      o[j] = packbf(W1[k0*NH1 + c], W1[(k0+1)*NH1 + c]);
    }
    *(uint4*)(w1p + s*4) = make_uint4(o[0],o[1],o[2],o[3]);
  }
  for(int s = tid; s < 1024; s += 256){          // W2: 4 nt x 4 kb frags
    int f = s >> 6, lane = s & 63;
    int nt = f >> 2, kb = f & 3, g = lane >> 4, c = nt*16 + (lane & 15);
    unsigned int o[4];
    #pragma unroll
    for(int j = 0; j < 4; j++){
      int k0 = kb*32 + g*8 + 2*j;
      o[j] = packbf(W2[k0*NEMB + c], W2[(k0+1)*NEMB + c]);
    }
    *(uint4*)(w2p + s*4) = make_uint4(o[0],o[1],o[2],o[3]);
  }
}

// ---------------- in-degree count ----------------
__global__ void k_count(const int* __restrict__ ei, const int* __restrict__ flag,
                        int* __restrict__ ideg, int E){
  int e = blockIdx.x*256 + threadIdx.x;
  if(e < E){
    bool is64 = (*flag != 0);
    int d = load_edge(ei, E + e, is64);
    atomicAdd(&ideg[d], 1);
  }
}

// ---------------- prefix sum ----------------
__global__ void k_scan1(const int* __restrict__ ideg, int* __restrict__ bsum, int n){
  __shared__ int red[256];
  int i0 = blockIdx.x*1024 + threadIdx.x*4;
  int t = 0;
  #pragma unroll
  for(int j = 0; j < 4; j++) if(i0+j < n) t += ideg[i0+j];
  red[threadIdx.x] = t;
  __syncthreads();
  for(int off = 128; off > 0; off >>= 1){
    if(threadIdx.x < off) red[threadIdx.x] += red[threadIdx.x + off];
    __syncthreads();
  }
  if(threadIdx.x == 0) bsum[blockIdx.x] = red[0];
}

// parallel Hillis-Steele over <=512 block sums (nblk = 391 here)
__global__ void k_scan2(int* __restrict__ bsum, int* __restrict__ row_start, int nblk, int n){
  __shared__ int sm[512];
  int t = threadIdx.x;
  int v = (t < nblk) ? bsum[t] : 0;
  sm[t] = v;
  __syncthreads();
  for(int off = 1; off < 512; off <<= 1){
    int a = (t >= off) ? sm[t - off] : 0;
    __syncthreads();
    sm[t] += a;
    __syncthreads();
  }
  if(t < nblk) bsum[t] = sm[t] - v;      // exclusive
  if(t == 511) row_start[n] = sm[511];   // total
}

__global__ void k_scan3(const int* __restrict__ ideg, const int* __restrict__ bsum,
                        int* __restrict__ row_start, int* __restrict__ cursor, int n){
  __shared__ int red[256];
  int i0 = blockIdx.x*1024 + threadIdx.x*4;
  int v[4]; int t = 0;
  #pragma unroll
  for(int j = 0; j < 4; j++){ v[j] = (i0+j < n) ? ideg[i0+j] : 0; t += v[j]; }
  red[threadIdx.x] = t;
  __syncthreads();
  for(int off = 1; off < 256; off <<= 1){
    int a = (threadIdx.x >= off) ? red[threadIdx.x - off] : 0;
    __syncthreads();
    red[threadIdx.x] += a;
    __syncthreads();
  }
  int run = bsum[blockIdx.x] + red[threadIdx.x] - t;
  #pragma unroll
  for(int j = 0; j < 4; j++){
    if(i0+j < n){ row_start[i0+j] = run; cursor[i0+j] = run; run += v[j]; }
  }
}

__global__ void k_dis(const int* __restrict__ ideg, float* __restrict__ dis, int n){
  int i = blockIdx.x*256 + threadIdx.x;
  if(i < n) dis[i] = rsqrtf((float)ideg[i] + 1.0f);   // +1 = self loop
}

__global__ void k_fill(const int* __restrict__ ei, const int* __restrict__ flag,
                       int* __restrict__ cursor, int* __restrict__ src_list, int E){
  int e = blockIdx.x*256 + threadIdx.x;
  if(e < E){
    bool is64 = (*flag != 0);
    int s = load_edge(ei, e, is64);
    int d = load_edge(ei, E + e, is64);
    int pos = atomicAdd(&cursor[d], 1);
    src_list[pos] = s;
  }
}

// ---------------- GEMM1 (MFMA): g1[n,128]bf16 = (x @ W1) * dis ----------------
// block = 256 thr = 4 waves; each wave: 16 nodes x 128 cols, K=64 (2 kb x 8 nt MFMAs)
__global__ __launch_bounds__(256) void k_gemm1m(const float* __restrict__ x, const unsigned int* __restrict__ w1p,
                                                const float* __restrict__ dis, unsigned int* __restrict__ g1, int n){
  __shared__ unsigned short tile[4][2176];     // 4 waves x [16][136] bf16
  const int tid = threadIdx.x;
  const int wm = tid >> 6, lane = tid & 63;
  const int m16 = lane & 15, g = lane >> 4;
  const int base = blockIdx.x*64;
  const int nodeA = base + wm*16 + m16;
  short8 a[2];
  #pragma unroll
  for(int kb = 0; kb < 2; kb++){
    float4 v0, v1;
    if(nodeA < n){
      const float* xp = x + (size_t)nodeA*FIN + kb*32 + g*8;
      v0 = *(const float4*)xp; v1 = *(const float4*)(xp + 4);
    } else { v0 = make_float4(0,0,0,0); v1 = v0; }
    U4S8 u;
    u.q.x = packbf(v0.x, v0.y); u.q.y = packbf(v0.z, v0.w);
    u.q.z = packbf(v1.x, v1.y); u.q.w = packbf(v1.z, v1.w);
    a[kb] = u.s;
  }
  f32x4 acc[8] = {};
  #pragma unroll
  for(int nt = 0; nt < 8; nt++){
    #pragma unroll
    for(int kb = 0; kb < 2; kb++){
      U4S8 b; b.q = *(const uint4*)(w1p + ((nt*2 + kb)*64 + lane)*4);
      acc[nt] = __builtin_amdgcn_mfma_f32_16x16x32_bf16(a[kb], b.s, acc[nt], 0, 0, 0);
    }
  }
  // epilogue: scale by dis, bf16, LDS transpose, coalesced store
  float dr[4];
  #pragma unroll
  for(int i = 0; i < 4; i++){ int r = base + wm*16 + 4*g + i; dr[i] = (r < n) ? dis[r] : 0.f; }
  unsigned short* T = tile[wm];
  #pragma unroll
  for(int nt = 0; nt < 8; nt++)
    #pragma unroll
    for(int i = 0; i < 4; i++)
      T[(4*g + i)*136 + nt*16 + m16] = (unsigned short)f2bf1(acc[nt][i] * dr[i]);
  __syncthreads();
  int r = lane >> 2;
  int node2 = base + wm*16 + r;
  if(node2 < n){
    uint4* dst = (uint4*)(g1 + (size_t)node2*64);
    #pragma unroll
    for(int j = 0; j < 4; j++){
      int q = (lane & 3)*4 + j;
      dst[q] = *(const uint4*)(T + r*136 + q*8);
    }
  }
}

// ---------------- fused layer1-aggregate + GEMM2 (MFMA) ----------------
// block = 256 thr, 64 nodes. Phase 1: 4 thr/node gather g1 + combine+ReLU -> x1 tile
// (bf16, row-major, XOR-swizzled) in LDS. Phase 2: MFMA x1 @ W2 -> g2 bf16.
__global__ __launch_bounds__(256) void k_fused1m(const unsigned int* __restrict__ g1, const unsigned int* __restrict__ w2p,
                                                 const float* __restrict__ dis, const float* __restrict__ b1,
                                                 const int* __restrict__ row_start, const int* __restrict__ src_list,
                                                 unsigned int* __restrict__ g2, int n){
  __shared__ unsigned int x1T[4352];    // 64 rows x 68 u32 (136 bf16), 17408 B
  const int tid = threadIdx.x;
  const int base = blockIdx.x*64;
  {
    int nl = tid >> 2, qc = tid & 3;    // node-local, channel quarter (32 ch)
    int node = base + nl;
    int rbase = nl*68 + qc*16;
    int sw = (nl & 7) << 2;
    if(node < n){
      float s[32];
      #pragma unroll
      for(int j = 0; j < 32; j++) s[j] = 0.f;
      const uint4* self = (const uint4*)(g1 + (size_t)node*64 + qc*16);
      { uint4 q0 = self[0], q1 = self[1], q2 = self[2], q3 = self[3];
        unp8add(s, q0); unp8add(s+8, q1); unp8add(s+16, q2); unp8add(s+24, q3); }
      int r0 = row_start[node], r1 = row_start[node+1];
      for(int e = r0; e < r1; e++){
        const uint4* p = (const uint4*)(g1 + (size_t)src_list[e]*64 + qc*16);
        uint4 q0 = p[0], q1 = p[1], q2 = p[2], q3 = p[3];
        unp8add(s, q0); unp8add(s+8, q1); unp8add(s+16, q2); unp8add(s+24, q3);
      }
      float d = dis[node];
      const float* bb = b1 + qc*32;
      unsigned int ob[16];
      #pragma unroll
      for(int j = 0; j < 16; j++){
        float v0 = fmaxf(fmaf(d, s[2*j],   bb[2*j]),   0.f);
        float v1 = fmaxf(fmaf(d, s[2*j+1], bb[2*j+1]), 0.f);
        ob[j] = packbf(v0, v1);
      }
      #pragma unroll
      for(int j = 0; j < 4; j++)
        *(uint4*)(x1T + ((rbase + j*4) ^ sw)) = make_uint4(ob[4*j], ob[4*j+1], ob[4*j+2], ob[4*j+3]);
    } else {
      #pragma unroll
      for(int j = 0; j < 4; j++)
        *(uint4*)(x1T + ((rbase + j*4) ^ sw)) = make_uint4(0,0,0,0);
    }
  }
  __syncthreads();
  const int wm = tid >> 6, lane = tid & 63, m16 = lane & 15, g = lane >> 4;
  const int row = wm*16 + m16;
  const int swr = (row & 7) << 2;
  f32x4 acc[4] = {};
  #pragma unroll
  for(int kb = 0; kb < 4; kb++){
    U4S8 a; a.q = *(const uint4*)(x1T + ((row*68 + kb*16 + g*4) ^ swr));
    #pragma unroll
    for(int nt = 0; nt < 4; nt++){
      U4S8 b; b.q = *(const uint4*)(w2p + ((nt*4 + kb)*64 + lane)*4);
      acc[nt] = __builtin_amdgcn_mfma_f32_16x16x32_bf16(a.s, b.s, acc[nt], 0, 0, 0);
    }
  }
  __syncthreads();                       // all reads of x1T done; reuse as transpose tile
  unsigned short* T = (unsigned short*)x1T + wm*1152;   // [16][72] bf16 per wave
  float dr[4];
  #pragma unroll
  for(int i = 0; i < 4; i++){ int r = base + wm*16 + 4*g + i; dr[i] = (r < n) ? dis[r] : 0.f; }
  #pragma unroll
  for(int nt = 0; nt < 4; nt++)
    #pragma unroll
    for(int i = 0; i < 4; i++)
      T[(4*g + i)*72 + nt*16 + m16] = (unsigned short)f2bf1(acc[nt][i] * dr[i]);
  __syncthreads();
  int r = lane >> 2;
  int node2 = base + wm*16 + r;
  if(node2 < n){
    uint4* dst = (uint4*)(g2 + (size_t)node2*32);
    #pragma unroll
    for(int j = 0; j < 2; j++){
      int q = ((lane & 3) << 1) + j;
      dst[q] = *(const uint4*)(T + r*72 + q*8);
    }
  }
}

// ---------------- fused layer2-aggregate + pool ----------------
// block = 256 thr, 64 nodes, 4 thr/node (16 ch each). out2 never materialized.
__global__ __launch_bounds__(256) void k_fused2p(const unsigned int* __restrict__ g2,
                                                 const float* __restrict__ dis, const float* __restrict__ b2,
                                                 const int* __restrict__ row_start, const int* __restrict__ src_list,
                                                 float* __restrict__ pooled, int n){
  __shared__ float red[256*17];
  const int tid = threadIdx.x;
  const int base = blockIdx.x*64;
  int nl = tid >> 2, qc = tid & 3;
  int node = base + nl;
  float s[16];
  #pragma unroll
  for(int j = 0; j < 16; j++) s[j] = 0.f;
  if(node < n){
    const uint4* self = (const uint4*)(g2 + (size_t)node*32 + qc*8);
    { uint4 q0 = self[0], q1 = self[1]; unp8add(s, q0); unp8add(s+8, q1); }
    int r0 = row_start[node], r1 = row_start[node+1];
    for(int e = r0; e < r1; e++){
      const uint4* p = (const uint4*)(g2 + (size_t)src_list[e]*32 + qc*8);
      uint4 q0 = p[0], q1 = p[1];
      unp8add(s, q0); unp8add(s+8, q1);
    }
    float d = dis[node];
    const float* bb = b2 + qc*16;
    #pragma unroll
    for(int j = 0; j < 16; j++) s[j] = fmaxf(fmaf(d, s[j], bb[j]), 0.f);
  }
  #pragma unroll
  for(int j = 0; j < 16; j++) red[tid*17 + j] = s[j];
  __syncthreads();
  if(tid < 64){
    int qc2 = tid >> 4, c = tid & 15;
    int b0 = base / NPER;
    int split = (b0 + 1)*NPER - base;     // m < split -> batch b0
    float s0 = 0.f, s1 = 0.f;
    for(int m = 0; m < 64; m++){
      float v = red[(m*4 + qc2)*17 + c];
      if(m < split) s0 += v; else s1 += v;
    }
    unsafeAtomicAdd(&pooled[b0*64 + qc2*16 + c], s0);
    if(split < 64 && b0 + 1 < NB) unsafeAtomicAdd(&pooled[(b0+1)*64 + qc2*16 + c], s1);
  }
}

// ---------------- head: out = relu(mean @ fc_w + fc_b) @ out_w + out_b ----------------
__global__ void k_head(const float* __restrict__ pooled, const float* __restrict__ fcw,
                       const float* __restrict__ fcb, const float* __restrict__ ow,
                       const float* __restrict__ ob, float* __restrict__ out){
  __shared__ float p[NB*NEMB];
  __shared__ float h[NB*NEMB];
  int t = threadIdx.x;                      // 0..511
  p[t] = pooled[t] * (1.0f / (float)NPER);
  __syncthreads();
  int b = t >> 6, j = t & 63;
  float a = fcb[j];
  #pragma unroll 8
  for(int c = 0; c < 64; c++) a = fmaf(p[b*64+c], fcw[c*64+j], a);
  h[t] = fmaxf(a, 0.f);
  __syncthreads();
  float o = ob[j];
  #pragma unroll 8
  for(int c = 0; c < 64; c++) o = fmaf(h[b*64+c], ow[c*64+j], o);
  out[t] = o;
}

extern "C" void kernel_launch(void* const* d_in, const int* in_sizes, int n_in,
                              void* d_out, int out_size, void* d_ws, size_t ws_size,
                              hipStream_t stream){
  const float* x   = (const float*)d_in[0];
  const int*   ei  = (const int*)d_in[1];
  const float* W1  = (const float*)d_in[2];
  const float* b1  = (const float*)d_in[3];
  const float* W2  = (const float*)d_in[4];
  const float* b2  = (const float*)d_in[5];
  const float* fcw = (const float*)d_in[6];
  const float* fcb = (const float*)d_in[7];
  const float* ow  = (const float*)d_in[8];
  const float* ob  = (const float*)d_in[9];

  const int n = in_sizes[0] / FIN;   // 400000 nodes
  const int E = in_sizes[1] / 2;     // 400000 edges

  char* p = (char*)d_ws;
  auto alloc = [&](size_t bytes){ char* r = p; p += (bytes + 255) & ~(size_t)255; return r; };
  float* dis      = (float*)alloc((size_t)n*4);
  int*   ideg     = (int*)  alloc((size_t)n*4);
  int*   row_start= (int*)  alloc((size_t)(n+1)*4);
  int*   cursor   = (int*)  alloc((size_t)n*4);
  int*   bsum     = (int*)  alloc(4096);
  int*   flag     = (int*)  alloc(256);
  float* pooled   = (float*)alloc(2048);
  unsigned int* w1p = (unsigned int*)alloc(16384);
  unsigned int* w2p = (unsigned int*)alloc(16384);
  int*   src_list = (int*)  alloc((size_t)E*4);
  unsigned int* g1 = (unsigned int*)alloc((size_t)n*64*4);   // [n,128] bf16
  unsigned int* g2 = (unsigned int*)alloc((size_t)n*32*4);   // [n,64]  bf16

  hipMemsetAsync(ideg, 0, (size_t)n*4, stream);
  hipMemsetAsync(pooled, 0, 2048, stream);

  k_detect<<<1, 256, 0, stream>>>(ei, flag);
  k_packW<<<1, 256, 0, stream>>>(W1, W2, w1p, w2p);
  k_count<<<(E+255)/256, 256, 0, stream>>>(ei, flag, ideg, E);
  int nblk = (n + 1023)/1024;
  k_scan1<<<nblk, 256, 0, stream>>>(ideg, bsum, n);
  k_scan2<<<1, 512, 0, stream>>>(bsum, row_start, nblk, n);
  k_scan3<<<nblk, 256, 0, stream>>>(ideg, bsum, row_start, cursor, n);
  k_dis<<<(n+255)/256, 256, 0, stream>>>(ideg, dis, n);
  k_fill<<<(E+255)/256, 256, 0, stream>>>(ei, flag, cursor, src_list, E);

  k_gemm1m<<<(n+63)/64, 256, 0, stream>>>(x, w1p, dis, g1, n);
  k_fused1m<<<(n+63)/64, 256, 0, stream>>>(g1, w2p, dis, b1, row_start, src_list, g2, n);
  k_fused2p<<<(n+63)/64, 256, 0, stream>>>(g2, dis, b2, row_start, src_list, pooled, n);

  k_head<<<1, 512, 0, stream>>>(pooled, fcw, fcb, ow, ob, (float*)d_out);
}

// Round 5
// 344.227 us; speedup vs baseline: 3.8571x; 1.1397x over previous
//
#include <hip/hip_runtime.h>

#define NPER 50000
#define NB 8
#define FIN 64
#define NH1 128
#define NEMB 64

typedef __attribute__((ext_vector_type(8))) short short8;
typedef __attribute__((ext_vector_type(4))) float f32x4;
union U4S8 { uint4 q; short8 s; };

// ---------------- bf16 helpers ----------------
__device__ inline float bf2f(unsigned int u){ union{unsigned int i; float f;} v; v.i = u<<16; return v.f; }
__device__ inline unsigned int f2bf1(float f){ union{float f; unsigned int i;} v; v.f = f;
  return (v.i + 0x7FFFu + ((v.i>>16)&1u)) >> 16; }
__device__ inline unsigned int packbf(float lo, float hi){ return f2bf1(lo) | (f2bf1(hi)<<16); }
__device__ inline void unp8add(float* s, uint4 q){
  s[0]+=bf2f(q.x&0xFFFFu); s[1]+=bf2f(q.x>>16);
  s[2]+=bf2f(q.y&0xFFFFu); s[3]+=bf2f(q.y>>16);
  s[4]+=bf2f(q.z&0xFFFFu); s[5]+=bf2f(q.z>>16);
  s[6]+=bf2f(q.w&0xFFFFu); s[7]+=bf2f(q.w>>16);
}
__device__ inline int load_edge(const int* __restrict__ ei, int idx, bool is64){
  return is64 ? ei[2*idx] : ei[idx];   // little-endian low word
}

// ---------------- k_init: detect dtype + packW + zero ideg/pooled, one launch ----------------
// k-mapping CHOSEN as k = kb*32 + 8*(lane/16) + i for both A and B fragments, so the
// contraction is correct regardless of the HW's internal k-permutation.
__global__ void k_init(const int* __restrict__ ei, const float* __restrict__ W1, const float* __restrict__ W2,
                       int* __restrict__ flag, unsigned int* __restrict__ w1p, unsigned int* __restrict__ w2p,
                       int* __restrict__ ideg, float* __restrict__ pooled, int n){
  const int b = blockIdx.x, tid = threadIdx.x;
  if(b == 0){
    __shared__ int any;
    if(tid == 0) any = 0;
    __syncthreads();
    for(int i = tid; i < 2048; i += 256) if(ei[2*i + 1] != 0) any = 1;
    __syncthreads();
    if(tid == 0) *flag = (any == 0) ? 1 : 0;   // 1 -> int64 storage
    if(tid < 256){ pooled[tid] = 0.f; pooled[tid + 256] = 0.f; }
  } else if(b == 1){
    for(int s = tid; s < 1024; s += 256){          // W1: 8 nt x 2 kb frags
      int f = s >> 6, lane = s & 63;
      int nt = f >> 1, kb = f & 1, g = lane >> 4, c = nt*16 + (lane & 15);
      unsigned int o[4];
      #pragma unroll
      for(int j = 0; j < 4; j++){
        int k0 = kb*32 + g*8 + 2*j;
        o[j] = packbf(W1[k0*NH1 + c], W1[(k0+1)*NH1 + c]);
      }
      *(uint4*)(w1p + s*4) = make_uint4(o[0],o[1],o[2],o[3]);
    }
    for(int s = tid; s < 1024; s += 256){          // W2: 4 nt x 4 kb frags
      int f = s >> 6, lane = s & 63;
      int nt = f >> 2, kb = f & 3, g = lane >> 4, c = nt*16 + (lane & 15);
      unsigned int o[4];
      #pragma unroll
      for(int j = 0; j < 4; j++){
        int k0 = kb*32 + g*8 + 2*j;
        o[j] = packbf(W2[k0*NEMB + c], W2[(k0+1)*NEMB + c]);
      }
      *(uint4*)(w2p + s*4) = make_uint4(o[0],o[1],o[2],o[3]);
    }
  } else {
    int i0 = (b-2)*4096 + tid*16;
    #pragma unroll
    for(int j = 0; j < 4; j++){
      int i = i0 + j*4;
      if(i + 3 < n) *(int4*)(ideg + i) = make_int4(0,0,0,0);
      else for(int k = 0; k < 4; k++) if(i + k < n) ideg[i+k] = 0;
    }
  }
}

// ---------------- in-degree count ----------------
__global__ void k_count(const int* __restrict__ ei, const int* __restrict__ flag,
                        int* __restrict__ ideg, int E){
  int e = blockIdx.x*256 + threadIdx.x;
  if(e < E){
    bool is64 = (*flag != 0);
    int d = load_edge(ei, E + e, is64);
    atomicAdd(&ideg[d], 1);
  }
}

// ---------------- prefix sum ----------------
__global__ void k_scan1(const int* __restrict__ ideg, int* __restrict__ bsum, int n){
  __shared__ int red[256];
  int i0 = blockIdx.x*1024 + threadIdx.x*4;
  int t = 0;
  #pragma unroll
  for(int j = 0; j < 4; j++) if(i0+j < n) t += ideg[i0+j];
  red[threadIdx.x] = t;
  __syncthreads();
  for(int off = 128; off > 0; off >>= 1){
    if(threadIdx.x < off) red[threadIdx.x] += red[threadIdx.x + off];
    __syncthreads();
  }
  if(threadIdx.x == 0) bsum[blockIdx.x] = red[0];
}

__global__ void k_scan2(int* __restrict__ bsum, int* __restrict__ row_start, int nblk, int n){
  __shared__ int sm[512];
  int t = threadIdx.x;
  int v = (t < nblk) ? bsum[t] : 0;
  sm[t] = v;
  __syncthreads();
  for(int off = 1; off < 512; off <<= 1){
    int a = (t >= off) ? sm[t - off] : 0;
    __syncthreads();
    sm[t] += a;
    __syncthreads();
  }
  if(t < nblk) bsum[t] = sm[t] - v;      // exclusive
  if(t == 511) row_start[n] = sm[511];   // total
}

// scan3 + dis + cursor (k_dis fused here)
__global__ void k_scan3(const int* __restrict__ ideg, const int* __restrict__ bsum,
                        int* __restrict__ row_start, int* __restrict__ cursor,
                        float* __restrict__ dis, int n){
  __shared__ int red[256];
  int i0 = blockIdx.x*1024 + threadIdx.x*4;
  int v[4]; int t = 0;
  #pragma unroll
  for(int j = 0; j < 4; j++){ v[j] = (i0+j < n) ? ideg[i0+j] : 0; t += v[j]; }
  red[threadIdx.x] = t;
  __syncthreads();
  for(int off = 1; off < 256; off <<= 1){
    int a = (threadIdx.x >= off) ? red[threadIdx.x - off] : 0;
    __syncthreads();
    red[threadIdx.x] += a;
    __syncthreads();
  }
  int run = bsum[blockIdx.x] + red[threadIdx.x] - t;
  #pragma unroll
  for(int j = 0; j < 4; j++){
    if(i0+j < n){
      row_start[i0+j] = run; cursor[i0+j] = run; run += v[j];
      dis[i0+j] = rsqrtf((float)v[j] + 1.0f);
    }
  }
}

__global__ void k_fill(const int* __restrict__ ei, const int* __restrict__ flag,
                       int* __restrict__ cursor, int* __restrict__ src_list, int E){
  int e = blockIdx.x*256 + threadIdx.x;
  if(e < E){
    bool is64 = (*flag != 0);
    int s = load_edge(ei, e, is64);
    int d = load_edge(ei, E + e, is64);
    int pos = atomicAdd(&cursor[d], 1);
    src_list[pos] = s;
  }
}

// ---------------- k_A: aggregate(x, fp32) -> GEMM1 -> ReLU -> GEMM2 -> g2 (bf16) ----------------
// block = 256 thr = 4 waves, 64 nodes. x1 never leaves LDS.
__global__ __launch_bounds__(256) void k_A(const float* __restrict__ x,
                                           const unsigned int* __restrict__ w1p, const unsigned int* __restrict__ w2p,
                                           const float* __restrict__ dis, const float* __restrict__ b1,
                                           const int* __restrict__ row_start, const int* __restrict__ src_list,
                                           unsigned int* __restrict__ g2, int n){
  __shared__ unsigned int aggT[64*36];     // [64 rows][32 u32 data + 4 pad], swizzle: row*36 + (off^sw)
  __shared__ unsigned int x1t[4][16*68];   // per-wave [16 rows][64 u32 data + 4 pad]
  __shared__ float sb1[NH1];
  const int tid = threadIdx.x;
  const int base = blockIdx.x*64;

  // ---- phase 1: dis-weighted gather of raw x (fp32), pack agg -> bf16 LDS ----
  if(tid < NH1) sb1[tid] = b1[tid];
  {
    const int nl = tid >> 2, qc = tid & 3;     // node-local, channel quarter (16 ch)
    const int node = base + nl;
    const int sw = (nl & 7) << 2;
    unsigned int* dst = aggT + nl*36;
    if(node < n){
      float dn = dis[node];
      float s[16];
      {
        const float4* xp = (const float4*)(x + (size_t)node*FIN + qc*16);
        float4 v0 = xp[0], v1 = xp[1], v2 = xp[2], v3 = xp[3];
        s[0]=dn*v0.x; s[1]=dn*v0.y; s[2]=dn*v0.z; s[3]=dn*v0.w;
        s[4]=dn*v1.x; s[5]=dn*v1.y; s[6]=dn*v1.z; s[7]=dn*v1.w;
        s[8]=dn*v2.x; s[9]=dn*v2.y; s[10]=dn*v2.z; s[11]=dn*v2.w;
        s[12]=dn*v3.x; s[13]=dn*v3.y; s[14]=dn*v3.z; s[15]=dn*v3.w;
      }
      int r0 = row_start[node], r1 = row_start[node+1];
      for(int e = r0; e < r1; e++){
        int src = src_list[e];
        float ds = dis[src];
        const float4* p = (const float4*)(x + (size_t)src*FIN + qc*16);
        float4 v0 = p[0], v1 = p[1], v2 = p[2], v3 = p[3];
        s[0]=fmaf(ds,v0.x,s[0]); s[1]=fmaf(ds,v0.y,s[1]); s[2]=fmaf(ds,v0.z,s[2]); s[3]=fmaf(ds,v0.w,s[3]);
        s[4]=fmaf(ds,v1.x,s[4]); s[5]=fmaf(ds,v1.y,s[5]); s[6]=fmaf(ds,v1.z,s[6]); s[7]=fmaf(ds,v1.w,s[7]);
        s[8]=fmaf(ds,v2.x,s[8]); s[9]=fmaf(ds,v2.y,s[9]); s[10]=fmaf(ds,v2.z,s[10]); s[11]=fmaf(ds,v2.w,s[11]);
        s[12]=fmaf(ds,v3.x,s[12]); s[13]=fmaf(ds,v3.y,s[13]); s[14]=fmaf(ds,v3.z,s[14]); s[15]=fmaf(ds,v3.w,s[15]);
      }
      unsigned int ob[8];
      #pragma unroll
      for(int j = 0; j < 8; j++) ob[j] = packbf(s[2*j]*dn, s[2*j+1]*dn);
      *(uint4*)(dst + ((qc*8    ) ^ sw)) = make_uint4(ob[0],ob[1],ob[2],ob[3]);
      *(uint4*)(dst + ((qc*8 + 4) ^ sw)) = make_uint4(ob[4],ob[5],ob[6],ob[7]);
    } else {
      *(uint4*)(dst + ((qc*8    ) ^ sw)) = make_uint4(0,0,0,0);
      *(uint4*)(dst + ((qc*8 + 4) ^ sw)) = make_uint4(0,0,0,0);
    }
  }
  __syncthreads();

  // ---- phase 2: GEMM1 (K=64) -> x1 = relu(acc + b1), bf16 into per-wave LDS tile ----
  const int wm = tid >> 6, lane = tid & 63, m16 = lane & 15, g = lane >> 4;
  {
    const int row = wm*16 + m16;
    const int swr = (row & 7) << 2;
    f32x4 acc[8] = {};
    #pragma unroll
    for(int kb = 0; kb < 2; kb++){
      U4S8 a; a.q = *(const uint4*)(aggT + row*36 + ((kb*16 + g*4) ^ swr));
      #pragma unroll
      for(int nt = 0; nt < 8; nt++){
        U4S8 b; b.q = *(const uint4*)(w1p + ((nt*2 + kb)*64 + lane)*4);
        acc[nt] = __builtin_amdgcn_mfma_f32_16x16x32_bf16(a.s, b.s, acc[nt], 0, 0, 0);
      }
    }
    // write x1 rows (node 4g+i, channel nt*16+m16) into wave tile, u32-granular swizzle
    unsigned short* T = (unsigned short*)x1t[wm];
    #pragma unroll
    for(int i = 0; i < 4; i++){
      int r = 4*g + i;
      int swx = (r & 7) << 2;
      #pragma unroll
      for(int nt = 0; nt < 8; nt++){
        int c = nt*16 + m16;
        float v = fmaxf(acc[nt][i] + sb1[c], 0.f);
        T[r*136 + 2*(((c >> 1) ^ swx)) + (c & 1)] = (unsigned short)f2bf1(v);
      }
    }
  }
  __syncthreads();

  // ---- phase 3: GEMM2 (K=128) on x1 tile ----
  f32x4 acc2[4] = {};
  {
    const int swr = (m16 & 7) << 2;
    #pragma unroll
    for(int kb = 0; kb < 4; kb++){
      U4S8 a; a.q = *(const uint4*)(x1t[wm] + m16*68 + ((kb*16 + g*4) ^ swr));
      #pragma unroll
      for(int nt = 0; nt < 4; nt++){
        U4S8 b; b.q = *(const uint4*)(w2p + ((nt*4 + kb)*64 + lane)*4);
        acc2[nt] = __builtin_amdgcn_mfma_f32_16x16x32_bf16(a.s, b.s, acc2[nt], 0, 0, 0);
      }
    }
  }
  __syncthreads();   // aggT reads long done; reuse as transpose tile

  // ---- phase 4: scale by dis, transpose via LDS, coalesced g2 store ----
  {
    unsigned short* T = (unsigned short*)aggT + wm*1152;   // [16][72] bf16 per wave
    float dr[4];
    #pragma unroll
    for(int i = 0; i < 4; i++){ int r = base + wm*16 + 4*g + i; dr[i] = (r < n) ? dis[r] : 0.f; }
    #pragma unroll
    for(int nt = 0; nt < 4; nt++)
      #pragma unroll
      for(int i = 0; i < 4; i++)
        T[(4*g + i)*72 + nt*16 + m16] = (unsigned short)f2bf1(acc2[nt][i] * dr[i]);
  }
  __syncthreads();
  {
    unsigned short* T = (unsigned short*)aggT + wm*1152;
    int r = lane >> 2;
    int node2 = base + wm*16 + r;
    if(node2 < n){
      uint4* dst = (uint4*)(g2 + (size_t)node2*32);
      #pragma unroll
      for(int j = 0; j < 2; j++){
        int q = ((lane & 3) << 1) + j;
        dst[q] = *(const uint4*)(T + r*72 + q*8);
      }
    }
  }
}

// ---------------- k_B: gather g2 + combine + ReLU + pool (out2 never materialized) ----------------
__global__ __launch_bounds__(256) void k_B(const unsigned int* __restrict__ g2,
                                           const float* __restrict__ dis, const float* __restrict__ b2,
                                           const int* __restrict__ row_start, const int* __restrict__ src_list,
                                           float* __restrict__ pooled, int n){
  __shared__ float red[256*17];
  const int tid = threadIdx.x;
  const int base = blockIdx.x*64;
  int nl = tid >> 2, qc = tid & 3;
  int node = base + nl;
  float s[16];
  #pragma unroll
  for(int j = 0; j < 16; j++) s[j] = 0.f;
  if(node < n){
    const uint4* self = (const uint4*)(g2 + (size_t)node*32 + qc*8);
    { uint4 q0 = self[0], q1 = self[1]; unp8add(s, q0); unp8add(s+8, q1); }
    int r0 = row_start[node], r1 = row_start[node+1];
    for(int e = r0; e < r1; e++){
      const uint4* p = (const uint4*)(g2 + (size_t)src_list[e]*32 + qc*8);
      uint4 q0 = p[0], q1 = p[1];
      unp8add(s, q0); unp8add(s+8, q1);
    }
    float d = dis[node];
    const float* bb = b2 + qc*16;
    #pragma unroll
    for(int j = 0; j < 16; j++) s[j] = fmaxf(fmaf(d, s[j], bb[j]), 0.f);
  }
  #pragma unroll
  for(int j = 0; j < 16; j++) red[tid*17 + j] = s[j];
  __syncthreads();
  if(tid < 64){
    int qc2 = tid >> 4, c = tid & 15;
    int b0 = base / NPER;
    int split = (b0 + 1)*NPER - base;     // m < split -> batch b0
    float s0 = 0.f, s1 = 0.f;
    for(int m = 0; m < 64; m++){
      float v = red[(m*4 + qc2)*17 + c];
      if(m < split) s0 += v; else s1 += v;
    }
    unsafeAtomicAdd(&pooled[b0*64 + qc2*16 + c], s0);
    if(split < 64 && b0 + 1 < NB) unsafeAtomicAdd(&pooled[(b0+1)*64 + qc2*16 + c], s1);
  }
}

// ---------------- head ----------------
__global__ void k_head(const float* __restrict__ pooled, const float* __restrict__ fcw,
                       const float* __restrict__ fcb, const float* __restrict__ ow,
                       const float* __restrict__ ob, float* __restrict__ out){
  __shared__ float p[NB*NEMB];
  __shared__ float h[NB*NEMB];
  int t = threadIdx.x;                      // 0..511
  p[t] = pooled[t] * (1.0f / (float)NPER);
  __syncthreads();
  int b = t >> 6, j = t & 63;
  float a = fcb[j];
  #pragma unroll 8
  for(int c = 0; c < 64; c++) a = fmaf(p[b*64+c], fcw[c*64+j], a);
  h[t] = fmaxf(a, 0.f);
  __syncthreads();
  float o = ob[j];
  #pragma unroll 8
  for(int c = 0; c < 64; c++) o = fmaf(h[b*64+c], ow[c*64+j], o);
  out[t] = o;
}

extern "C" void kernel_launch(void* const* d_in, const int* in_sizes, int n_in,
                              void* d_out, int out_size, void* d_ws, size_t ws_size,
                              hipStream_t stream){
  const float* x   = (const float*)d_in[0];
  const int*   ei  = (const int*)d_in[1];
  const float* W1  = (const float*)d_in[2];
  const float* b1  = (const float*)d_in[3];
  const float* W2  = (const float*)d_in[4];
  const float* b2  = (const float*)d_in[5];
  const float* fcw = (const float*)d_in[6];
  const float* fcb = (const float*)d_in[7];
  const float* ow  = (const float*)d_in[8];
  const float* ob  = (const float*)d_in[9];

  const int n = in_sizes[0] / FIN;   // 400000 nodes
  const int E = in_sizes[1] / 2;     // 400000 edges

  char* p = (char*)d_ws;
  auto alloc = [&](size_t bytes){ char* r = p; p += (bytes + 255) & ~(size_t)255; return r; };
  float* dis      = (float*)alloc((size_t)n*4);
  int*   ideg     = (int*)  alloc((size_t)n*4);
  int*   row_start= (int*)  alloc((size_t)(n+1)*4);
  int*   cursor   = (int*)  alloc((size_t)n*4);
  int*   bsum     = (int*)  alloc(4096);
  int*   flag     = (int*)  alloc(256);
  float* pooled   = (float*)alloc(2048);
  unsigned int* w1p = (unsigned int*)alloc(16384);
  unsigned int* w2p = (unsigned int*)alloc(16384);
  int*   src_list = (int*)  alloc((size_t)E*4);
  unsigned int* g2 = (unsigned int*)alloc((size_t)n*32*4);   // [n,64] bf16

  int zblk = (n + 4095)/4096;
  k_init<<<2 + zblk, 256, 0, stream>>>(ei, W1, W2, flag, w1p, w2p, ideg, pooled, n);
  k_count<<<(E+255)/256, 256, 0, stream>>>(ei, flag, ideg, E);
  int nblk = (n + 1023)/1024;
  k_scan1<<<nblk, 256, 0, stream>>>(ideg, bsum, n);
  k_scan2<<<1, 512, 0, stream>>>(bsum, row_start, nblk, n);
  k_scan3<<<nblk, 256, 0, stream>>>(ideg, bsum, row_start, cursor, dis, n);
  k_fill<<<(E+255)/256, 256, 0, stream>>>(ei, flag, cursor, src_list, E);

  k_A<<<(n+63)/64, 256, 0, stream>>>(x, w1p, w2p, dis, b1, row_start, src_list, g2, n);
  k_B<<<(n+63)/64, 256, 0, stream>>>(g2, dis, b2, row_start, src_list, pooled, n);
  k_head<<<1, 512, 0, stream>>>(pooled, fcw, fcb, ow, ob, (float*)d_out);
}